// Round 2
// baseline (32.479 us; speedup 1.0000x reference)
//
#include <hip/hip_runtime.h>

#define RC2   6.25f     // (2.5*sigma)^2
#define CINV  0.4f      // 1/2.5 cell width
#define NC    8         // cells per dimension
#define NCELLS 512
#define MAXP  96        // capacity per cell (mean ~16, Poisson tail ~0)
#define NBCAP (27 * MAXP)

__device__ __forceinline__ float wave_reduce_sum(float v) {
    #pragma unroll
    for (int off = 32; off > 0; off >>= 1)
        v += __shfl_down(v, off, 64);
    return v;
}

__global__ __launch_bounds__(256) void lj_build(const float* __restrict__ pos, int N,
                                                int* __restrict__ cnt,
                                                float4* __restrict__ cellPos) {
    int i = blockIdx.x * 256 + threadIdx.x;
    if (i >= N) return;
    float x = pos[3 * i + 0];
    float y = pos[3 * i + 1];
    float z = pos[3 * i + 2];
    int cx = (int)(x * CINV); cx = cx < 0 ? 0 : (cx > NC - 1 ? NC - 1 : cx);
    int cy = (int)(y * CINV); cy = cy < 0 ? 0 : (cy > NC - 1 ? NC - 1 : cy);
    int cz = (int)(z * CINV); cz = cz < 0 ? 0 : (cz > NC - 1 ? NC - 1 : cz);
    int c = (cz * NC + cy) * NC + cx;
    int slot = atomicAdd(&cnt[c], 1);
    if (slot < MAXP) {
        cellPos[c * MAXP + slot] = make_float4(x, y, z, __int_as_float(i));
    }
}

__global__ __launch_bounds__(256) void lj_pairs(const int* __restrict__ cnt,
                                                const float4* __restrict__ cellPos,
                                                float* __restrict__ partial) {
    __shared__ float4 nb[NBCAP];   // 27*96*16B = 41.5 KB
    const int c = blockIdx.x;
    const int cx = c & 7, cy = (c >> 3) & 7, cz = c >> 6;

    // Gather up to 27 neighbor cells (incl. own) into a packed LDS list.
    int n_nb = 0;
    int offMine = 0;
    for (int dz = -1; dz <= 1; ++dz) {
        int zz = cz + dz;
        if ((unsigned)zz >= NC) continue;
        for (int dy = -1; dy <= 1; ++dy) {
            int yy = cy + dy;
            if ((unsigned)yy >= NC) continue;
            for (int dx = -1; dx <= 1; ++dx) {
                int xx = cx + dx;
                if ((unsigned)xx >= NC) continue;
                int cc = (zz * NC + yy) * NC + xx;
                int n = cnt[cc]; n = n > MAXP ? MAXP : n;
                if (cc == c) offMine = n_nb;
                const float4* src = cellPos + cc * MAXP;
                for (int t = threadIdx.x; t < n; t += 256)
                    nb[n_nb + t] = src[t];
                n_nb += n;
            }
        }
    }
    __syncthreads();

    int nI = cnt[c]; nI = nI > MAXP ? MAXP : nI;
    float e = 0.0f;
    for (int i = 0; i < nI; ++i) {
        float4 pi = nb[offMine + i];          // LDS broadcast (uniform addr)
        int ii = __float_as_int(pi.w);
        for (int jt = threadIdx.x; jt < n_nb; jt += 256) {
            float4 pj = nb[jt];               // ds_read_b128, conflict-free
            float ddx = pi.x - pj.x;
            float ddy = pi.y - pj.y;
            float ddz = pi.z - pj.z;
            float r2 = ddx * ddx + ddy * ddy + ddz * ddz;
            bool ok = (r2 < RC2) && (__float_as_int(pj.w) != ii);
            float inv = ok ? __builtin_amdgcn_rcpf(r2) : 0.0f;
            float sr6 = inv * inv * inv;
            e += sr6 * sr6 - sr6;             // (sr12 - sr6), ordered pair
        }
    }

    // deterministic block reduction -> one partial per cell
    __shared__ float ssum[4];
    float w = wave_reduce_sum(e);
    int lane = threadIdx.x & 63;
    int wid  = threadIdx.x >> 6;
    if (lane == 0) ssum[wid] = w;
    __syncthreads();
    if (threadIdx.x == 0)
        partial[c] = ssum[0] + ssum[1] + ssum[2] + ssum[3];
}

__global__ __launch_bounds__(256) void lj_reduce(const float* __restrict__ partial,
                                                 int n, float* __restrict__ out) {
    float v = 0.0f;
    for (int idx = threadIdx.x; idx < n; idx += 256) v += partial[idx];
    float w = wave_reduce_sum(v);
    __shared__ float ssum[4];
    int lane = threadIdx.x & 63;
    int wid  = threadIdx.x >> 6;
    if (lane == 0) ssum[wid] = w;
    __syncthreads();
    if (threadIdx.x == 0) {
        // ordered-pair sum * 0.5 (each pair counted twice) * 4*EPSILON
        out[0] = 2.0f * (ssum[0] + ssum[1] + ssum[2] + ssum[3]);
    }
}

extern "C" void kernel_launch(void* const* d_in, const int* in_sizes, int n_in,
                              void* d_out, int out_size, void* d_ws, size_t ws_size,
                              hipStream_t stream) {
    const float* pos = (const float*)d_in[0];
    float* out = (float*)d_out;

    // ws layout: [0..2KB) cell counts | [2KB..4KB) partials | [4KB..) cellPos
    int*    cnt     = (int*)d_ws;
    float*  partial = (float*)((char*)d_ws + 2048);
    float4* cellPos = (float4*)((char*)d_ws + 4096);

    int N = in_sizes[0] / 3;

    hipMemsetAsync(cnt, 0, NCELLS * sizeof(int), stream);
    lj_build<<<(N + 255) / 256, 256, 0, stream>>>(pos, N, cnt, cellPos);
    lj_pairs<<<NCELLS, 256, 0, stream>>>(cnt, cellPos, partial);
    lj_reduce<<<1, 256, 0, stream>>>(partial, NCELLS, out);
}

// Round 3
// 30.370 us; speedup vs baseline: 1.0695x; 1.0695x over previous
//
#include <hip/hip_runtime.h>

#define RC2    6.25f    // (2.5*sigma)^2
#define CINV   0.4f     // 1/2.5 cell width
#define NC     8        // cells per dimension
#define NCELLS 512
#define MAXP   96       // capacity per cell (mean ~16)
#define NBMAX  (14 * MAXP)

// own cell + 13 lexicographically-positive offsets (dz major, then dy, dx)
__device__ const signed char HOFF[14][3] = {
    { 0, 0, 0},
    { 1, 0, 0},
    {-1, 1, 0}, { 0, 1, 0}, { 1, 1, 0},
    {-1,-1, 1}, { 0,-1, 1}, { 1,-1, 1},
    {-1, 0, 1}, { 0, 0, 1}, { 1, 0, 1},
    {-1, 1, 1}, { 0, 1, 1}, { 1, 1, 1}
};

__device__ __forceinline__ float wave_reduce_sum(float v) {
    #pragma unroll
    for (int off = 32; off > 0; off >>= 1)
        v += __shfl_down(v, off, 64);
    return v;
}

__global__ __launch_bounds__(256) void lj_build(const float* __restrict__ pos, int N,
                                                int* __restrict__ cnt,
                                                float4* __restrict__ cellPos) {
    int i = blockIdx.x * 256 + threadIdx.x;
    if (i >= N) return;
    float x = pos[3 * i + 0];
    float y = pos[3 * i + 1];
    float z = pos[3 * i + 2];
    int cx = (int)(x * CINV); cx = cx < 0 ? 0 : (cx > NC - 1 ? NC - 1 : cx);
    int cy = (int)(y * CINV); cy = cy < 0 ? 0 : (cy > NC - 1 ? NC - 1 : cy);
    int cz = (int)(z * CINV); cz = cz < 0 ? 0 : (cz > NC - 1 ? NC - 1 : cz);
    int c = (cz * NC + cy) * NC + cx;
    int slot = atomicAdd(&cnt[c], 1);
    if (slot < MAXP) {
        cellPos[c * MAXP + slot] = make_float4(x, y, z, 0.0f);
    }
}

__global__ __launch_bounds__(256) void lj_pairs(const int* __restrict__ cnt,
                                                const float4* __restrict__ cellPos,
                                                float* __restrict__ partial,
                                                int* __restrict__ ticket,
                                                float* __restrict__ out) {
    const int c  = blockIdx.x;
    const int cx = c & 7, cy = (c >> 3) & 7, cz = c >> 6;
    const int tid = threadIdx.x;

    __shared__ float4 nb[NBMAX];          // ~21.5 KB
    __shared__ int s_cnt[14], s_base[14], s_off[15];

    // 14 parallel count loads (no serialized dependency chain)
    if (tid < 14) {
        int xx = cx + HOFF[tid][0];
        int yy = cy + HOFF[tid][1];
        int zz = cz + HOFF[tid][2];
        bool ok = ((unsigned)xx < NC) & ((unsigned)yy < NC) & ((unsigned)zz < NC);
        int cc = (zz * NC + yy) * NC + xx;
        int n = ok ? cnt[cc] : 0;
        s_cnt[tid]  = n > MAXP ? MAXP : n;
        s_base[tid] = cc * MAXP;
    }
    __syncthreads();
    if (tid == 0) {
        int acc = 0;
        #pragma unroll
        for (int k = 0; k < 14; ++k) { s_off[k] = acc; acc += s_cnt[k]; }
        s_off[14] = acc;
    }
    __syncthreads();

    // cooperative flat-index copy of all 14 cells into LDS (own cell first)
    const int total = s_off[14];
    for (int f = tid; f < total; f += 256) {
        int k = 0;
        while (f >= s_off[k + 1]) ++k;
        nb[f] = cellPos[s_base[k] + (f - s_off[k])];
    }
    __syncthreads();

    // half-shell sweep: particle i (own cell, staged at [0,nI)) pairs with all
    // staged entries at index > i. Own-cell pairs counted once via slot order;
    // cross-cell pairs once via lexicographic cell selection.
    const int nI = s_cnt[0];
    float e = 0.0f;
    for (int i = 0; i < nI; ++i) {
        float4 pi = nb[i];                     // uniform addr -> LDS broadcast
        for (int jt = i + 1 + tid; jt < total; jt += 256) {
            float4 pj = nb[jt];
            float dx = pi.x - pj.x;
            float dy = pi.y - pj.y;
            float dz = pi.z - pj.z;
            float r2 = dx * dx + dy * dy + dz * dz;
            bool ok = (r2 < RC2);
            float inv = ok ? __builtin_amdgcn_rcpf(r2) : 0.0f;
            float sr6 = inv * inv * inv;
            e += sr6 * sr6 - sr6;              // each unique pair exactly once
        }
    }

    // block reduction (fixed tree -> deterministic order)
    __shared__ float ssum[4];
    float w = wave_reduce_sum(e);
    if ((tid & 63) == 0) ssum[tid >> 6] = w;
    __syncthreads();

    __shared__ int s_ticket;
    if (tid == 0) {
        float bsum = ssum[0] + ssum[1] + ssum[2] + ssum[3];
        atomicExch(&partial[c], bsum);         // device-scope visible store
        __threadfence();
        s_ticket = atomicAdd(ticket, 1);
    }
    __syncthreads();

    // last arriving block performs the final (fixed-order) reduction
    if (s_ticket == NCELLS - 1) {
        __threadfence();
        float v = 0.0f;
        for (int idx = tid; idx < NCELLS; idx += 256)
            v += atomicAdd(&partial[idx], 0.0f);   // coherent read
        float w2 = wave_reduce_sum(v);
        if ((tid & 63) == 0) ssum[tid >> 6] = w2;
        __syncthreads();
        if (tid == 0)
            out[0] = 4.0f * (ssum[0] + ssum[1] + ssum[2] + ssum[3]);
    }
}

extern "C" void kernel_launch(void* const* d_in, const int* in_sizes, int n_in,
                              void* d_out, int out_size, void* d_ws, size_t ws_size,
                              hipStream_t stream) {
    const float* pos = (const float*)d_in[0];
    float* out = (float*)d_out;

    // ws layout: [0,2048) cnt | [2048,2052) ticket | [2112,4160) partial | [4608,..) cellPos
    int*    cnt     = (int*)d_ws;
    int*    ticket  = (int*)((char*)d_ws + 2048);
    float*  partial = (float*)((char*)d_ws + 2112);
    float4* cellPos = (float4*)((char*)d_ws + 4608);

    int N = in_sizes[0] / 3;

    hipMemsetAsync(d_ws, 0, 2052, stream);     // cnt + ticket
    lj_build<<<(N + 255) / 256, 256, 0, stream>>>(pos, N, cnt, cellPos);
    lj_pairs<<<NCELLS, 256, 0, stream>>>(cnt, cellPos, partial, ticket, out);
}

// Round 4
// 22.935 us; speedup vs baseline: 1.4162x; 1.3242x over previous
//
#include <hip/hip_runtime.h>

#define RC2    6.25f    // (2.5*sigma)^2
#define CINV   0.4f     // 1/cell width
#define NC     8
#define NCELLS 512
#define MAXOWN 128      // Poisson(16) -> 128 is ultra-safe
#define MAXNB  512      // 13 cells, Poisson(208) -> 512 is ultra-safe

__device__ __forceinline__ float wave_reduce_sum(float v) {
    #pragma unroll
    for (int off = 32; off > 0; off >>= 1)
        v += __shfl_down(v, off, 64);
    return v;
}

// One block per cell. Scans all positions (L2-resident), keeps own-cell
// particles and particles in the 13 lexicographically-positive neighbor
// cells, then evaluates each unique pair exactly once:
//   - own-vs-own with slot index i<j
//   - own-vs-neighborhood (half-shell -> every cross-cell pair counted once)
__global__ __launch_bounds__(256) void lj_fused(const float* __restrict__ pos, int N,
                                                float* __restrict__ partial) {
    const int c  = blockIdx.x;
    const int cx = c & 7, cy = (c >> 3) & 7, cz = c >> 6;
    const int tid = threadIdx.x;

    __shared__ float4 own[MAXOWN];
    __shared__ float4 nbl[MAXNB];
    __shared__ int s_nOwn, s_nNb;
    if (tid == 0) { s_nOwn = 0; s_nNb = 0; }
    __syncthreads();

    // classify-scan: delta code (dz+1,dy+1,dx+1) base-3; 13 == own cell,
    // >13 == lexicographically-positive neighbor (half shell)
    for (int p = tid; p < N; p += 256) {
        float x = pos[3 * p + 0];
        float y = pos[3 * p + 1];
        float z = pos[3 * p + 2];
        int dx = min((int)(x * CINV), NC - 1) - cx + 1;
        int dy = min((int)(y * CINV), NC - 1) - cy + 1;
        int dz = min((int)(z * CINV), NC - 1) - cz + 1;
        if ((unsigned)dx < 3u && (unsigned)dy < 3u && (unsigned)dz < 3u) {
            int code = (dz * 3 + dy) * 3 + dx;
            if (code == 13) {
                int s = atomicAdd(&s_nOwn, 1);
                if (s < MAXOWN) own[s] = make_float4(x, y, z, 0.0f);
            } else if (code > 13) {
                int s = atomicAdd(&s_nNb, 1);
                if (s < MAXNB) nbl[s] = make_float4(x, y, z, 0.0f);
            }
        }
    }
    __syncthreads();

    const int nOwn = min(s_nOwn, MAXOWN);
    const int nNb  = min(s_nNb, MAXNB);

    float e = 0.0f;
    for (int i = 0; i < nOwn; ++i) {
        float4 pi = own[i];                  // uniform addr -> LDS broadcast
        // own-cell pairs (i < j), counted once
        for (int j = i + 1 + tid; j < nOwn; j += 256) {
            float4 pj = own[j];
            float ddx = pi.x - pj.x;
            float ddy = pi.y - pj.y;
            float ddz = pi.z - pj.z;
            float r2 = ddx * ddx + ddy * ddy + ddz * ddz;
            bool ok = (r2 < RC2);
            float inv = ok ? __builtin_amdgcn_rcpf(r2) : 0.0f;
            float sr6 = inv * inv * inv;
            e += sr6 * sr6 - sr6;
        }
        // cross-cell half-shell pairs, counted once
        for (int j = tid; j < nNb; j += 256) {
            float4 pj = nbl[j];
            float ddx = pi.x - pj.x;
            float ddy = pi.y - pj.y;
            float ddz = pi.z - pj.z;
            float r2 = ddx * ddx + ddy * ddy + ddz * ddz;
            bool ok = (r2 < RC2);
            float inv = ok ? __builtin_amdgcn_rcpf(r2) : 0.0f;
            float sr6 = inv * inv * inv;
            e += sr6 * sr6 - sr6;
        }
    }

    // deterministic block reduction -> one partial per cell (plain store;
    // kernel-boundary coherence covers the reduce kernel)
    __shared__ float ssum[4];
    float w = wave_reduce_sum(e);
    if ((tid & 63) == 0) ssum[tid >> 6] = w;
    __syncthreads();
    if (tid == 0)
        partial[c] = ssum[0] + ssum[1] + ssum[2] + ssum[3];
}

__global__ __launch_bounds__(256) void lj_reduce(const float* __restrict__ partial,
                                                 float* __restrict__ out) {
    float v = 0.0f;
    for (int idx = threadIdx.x; idx < NCELLS; idx += 256) v += partial[idx];
    float w = wave_reduce_sum(v);
    __shared__ float ssum[4];
    if ((threadIdx.x & 63) == 0) ssum[threadIdx.x >> 6] = w;
    __syncthreads();
    if (threadIdx.x == 0)
        out[0] = 4.0f * (ssum[0] + ssum[1] + ssum[2] + ssum[3]);  // 4*EPSILON*(sr12-sr6)
}

extern "C" void kernel_launch(void* const* d_in, const int* in_sizes, int n_in,
                              void* d_out, int out_size, void* d_ws, size_t ws_size,
                              hipStream_t stream) {
    const float* pos = (const float*)d_in[0];
    float* out = (float*)d_out;
    float* partial = (float*)d_ws;

    int N = in_sizes[0] / 3;

    lj_fused<<<NCELLS, 256, 0, stream>>>(pos, N, partial);
    lj_reduce<<<1, 256, 0, stream>>>(partial, out);
}